// Round 4
// baseline (14852.957 us; speedup 1.0000x reference)
//
#include <hip/hip_runtime.h>

#define B_  64
#define T_  2048
#define I_  128
#define H_  256
#define G4  1024   // 4*H
#define TC  128    // timestep chunk

typedef float    f32x4 __attribute__((ext_vector_type(4)));
typedef _Float16 f16x8 __attribute__((ext_vector_type(8)));
typedef _Float16 f16x2 __attribute__((ext_vector_type(2)));

__device__ __forceinline__ float dot2f(unsigned w, unsigned h, float acc) {
#if __has_builtin(__builtin_amdgcn_fdot2)
  return __builtin_amdgcn_fdot2(__builtin_bit_cast(f16x2, w),
                                __builtin_bit_cast(f16x2, h), acc, false);
#else
  f16x2 a = __builtin_bit_cast(f16x2, w), b = __builtin_bit_cast(f16x2, h);
  return acc + (float)a[0] * (float)b[0] + (float)a[1] * (float)b[1];
#endif
}

__device__ __forceinline__ unsigned short h16bits(float f) {
  return __builtin_bit_cast(unsigned short, (_Float16)f);
}
__device__ __forceinline__ float sigm(float x) { return 1.f / (1.f + __expf(-x)); }
__device__ __forceinline__ float tanh_fast(float x) { return 2.f / (1.f + __expf(-2.f * x)) - 1.f; }

// ---------------- prep kernels ----------------

// W_hh [1024][256] f32 -> packed f16x2 dwords, split into:
//   wregg: [24][1024] uint4  (k-dwords 0..95  -> register-resident in scan)
//   wldsg: [8][1024]  uint4  (k-dwords 96..127 -> LDS-resident in scan)
__global__ void prep_w(const float* __restrict__ Whh,
                       uint4* __restrict__ wregg, uint4* __restrict__ wldsg) {
  int idx = blockIdx.x * 256 + threadIdx.x;   // 0..32767
  if (idx >= 32 * 1024) return;
  int c4 = idx >> 10, r = idx & 1023;         // c4: uint4 index 0..31 along k
  unsigned q[4];
#pragma unroll
  for (int m = 0; m < 4; m++) {
    int kd = 4 * c4 + m;                      // dword index 0..127
    unsigned lo = h16bits(Whh[r * 256 + 2 * kd]);
    unsigned hi = h16bits(Whh[r * 256 + 2 * kd + 1]);
    q[m] = lo | (hi << 16);
  }
  uint4 v = make_uint4(q[0], q[1], q[2], q[3]);
  if (c4 < 24) wregg[c4 * 1024 + r] = v;
  else         wldsg[(c4 - 24) * 1024 + r] = v;
}

__global__ void prep_f16(const float* __restrict__ src, _Float16* __restrict__ dst, int n) {
  int i = blockIdx.x * 256 + threadIdx.x;
  if (i < n) dst[i] = (_Float16)src[i];
}

__global__ void prep_bias(const float* __restrict__ bi, const float* __restrict__ bh,
                          float* __restrict__ bias) {
  int i = blockIdx.x * 256 + threadIdx.x;
  if (i < G4) bias[i] = bi[i] + bh[i];
}

// ---------------- projection GEMM (f16 MFMA) ----------------
template <int K, bool SRC_F32>
__global__ __launch_bounds__(256) void proj_kernel(const void* __restrict__ Asrc,
                                                   const _Float16* __restrict__ Wf,
                                                   const float* __restrict__ bias,
                                                   float* __restrict__ xw, int t0) {
  const int m  = blockIdx.x;        // M-tile (64 rows)
  const int n0 = blockIdx.y * 64;   // N-tile base
  const int tid = threadIdx.x;
  const int lane = tid & 63, wv = tid >> 6;

  __shared__ _Float16 As[64][40];
  __shared__ _Float16 Bs[64][40];

  f32x4 acc[4] = {f32x4{0,0,0,0}, f32x4{0,0,0,0}, f32x4{0,0,0,0}, f32x4{0,0,0,0}};

  const int r  = tid >> 2;
  const int kq = (tid & 3) * 8;
  const int r_g = m * 64 + r;
  const int b  = r_g >> 7;          // TC = 128
  const int tc = r_g & (TC - 1);
  long arow;
  if (SRC_F32) arow = (long)(b * T_ + t0 + tc) * K;
  else         arow = (long)r_g * K;

  for (int k0 = 0; k0 < K; k0 += 32) {
    if (SRC_F32) {
      const float* ap = (const float*)Asrc + arow + k0 + kq;
      float4 a0 = *(const float4*)ap;
      float4 a1 = *(const float4*)(ap + 4);
      _Float16* d = &As[r][kq];
      d[0] = (_Float16)a0.x; d[1] = (_Float16)a0.y; d[2] = (_Float16)a0.z; d[3] = (_Float16)a0.w;
      d[4] = (_Float16)a1.x; d[5] = (_Float16)a1.y; d[6] = (_Float16)a1.z; d[7] = (_Float16)a1.w;
    } else {
      const _Float16* ap = (const _Float16*)Asrc + arow + k0 + kq;
      *(uint4*)&As[r][kq] = *(const uint4*)ap;
    }
    *(uint4*)&Bs[r][kq] = *(const uint4*)(Wf + (long)(n0 + r) * K + k0 + kq);
    __syncthreads();

    f16x8 av = *(const f16x8*)&As[wv * 16 + (lane & 15)][(lane >> 4) * 8];
#pragma unroll
    for (int q = 0; q < 4; q++) {
      f16x8 bv = *(const f16x8*)&Bs[q * 16 + (lane & 15)][(lane >> 4) * 8];
      acc[q] = __builtin_amdgcn_mfma_f32_16x16x32_f16(av, bv, acc[q], 0, 0, 0);
    }
    __syncthreads();
  }

  const int row_in = wv * 16 + ((lane >> 4) << 2);
  const int col_in = lane & 15;
#pragma unroll
  for (int q = 0; q < 4; q++) {
#pragma unroll
    for (int i = 0; i < 4; i++) {
      int rr = m * 64 + row_in + i;
      int cc = n0 + q * 16 + col_in;
      xw[(long)rr * G4 + cc] = acc[q][i] + bias[cc];
    }
  }
}

// ---------------- recurrent scan ----------------
// One block (256 threads) per batch element. Thread j owns h-index j and all
// four gate rows {j, j+256, j+512, j+768}: gate combine is thread-local.
// W head (k-dwords 0..95): 96 named uint4, PINNED via asm so the register
// allocator cannot rematerialize the (invariant) global loads into the loop.
// W tail (96..127): LDS-resident (128 KB).

#define C24(X) X(0) X(1) X(2) X(3) X(4) X(5) X(6) X(7) X(8) X(9) X(10) X(11) \
               X(12) X(13) X(14) X(15) X(16) X(17) X(18) X(19) X(20) X(21) X(22) X(23)

#define LOADC(c) \
  uint4 w0_##c = wregg[(c) * 1024 + j]; \
  uint4 w1_##c = wregg[(c) * 1024 + j + 256]; \
  uint4 w2_##c = wregg[(c) * 1024 + j + 512]; \
  uint4 w3_##c = wregg[(c) * 1024 + j + 768];

// Pin: make each loaded dword an opaque register value (not rematerializable).
#define PINC(c) \
  asm volatile("" : "+v"(w0_##c.x), "+v"(w0_##c.y), "+v"(w0_##c.z), "+v"(w0_##c.w), \
                    "+v"(w1_##c.x), "+v"(w1_##c.y), "+v"(w1_##c.z), "+v"(w1_##c.w), \
                    "+v"(w2_##c.x), "+v"(w2_##c.y), "+v"(w2_##c.z), "+v"(w2_##c.w), \
                    "+v"(w3_##c.x), "+v"(w3_##c.y), "+v"(w3_##c.z), "+v"(w3_##c.w));

#define DOT4(e, c, hw) \
  a0 = dot2f(w0_##c.e, hw, a0); a1 = dot2f(w1_##c.e, hw, a1); \
  a2 = dot2f(w2_##c.e, hw, a2); a3 = dot2f(w3_##c.e, hw, a3);

#define DOTC(c) { uint4 hv = hp[c]; \
  DOT4(x, c, hv.x) DOT4(y, c, hv.y) DOT4(z, c, hv.z) DOT4(w, c, hv.w) }

__global__ __launch_bounds__(256, 1) void scan_kernel(
    const float* __restrict__ xw,      // [B*TC][1024] chunk
    const uint4* __restrict__ wregg,   // [24][1024]
    const uint4* __restrict__ wldsg,   // [8][1024]
    const float* __restrict__ mask,    // [B][256]
    float* __restrict__ hstate, float* __restrict__ cstate,  // [B][256]
    _Float16* __restrict__ ychunk,     // layer0 out chunk (or null)
    float* __restrict__ out,           // layer1: d_out base (or null)
    float* __restrict__ hn, float* __restrict__ cn,          // last chunk only
    int t0) {
  const int b = blockIdx.x;
  const int j = threadIdx.x;

  __shared__ uint4    wt_lds[8 * 1024];   // 128KB W tail, [q4][row]
  __shared__ unsigned hsb[2][128];        // double-buffered h, packed f16x2

  // stage W tail into LDS (coalesced, conflict-free)
#pragma unroll
  for (int i = 0; i < 32; i++)
    wt_lds[i * 256 + j] = wldsg[i * 256 + j];

  // W head into 96 named uint4 (384 VGPRs), pinned against remat
  C24(LOADC)
  C24(PINC)

  float c_reg = cstate[b * 256 + j];
  float h_reg = hstate[b * 256 + j];
  const float mk = mask[b * 256 + j];
  ((unsigned short*)&hsb[0][0])[j] = h16bits(h_reg);
  __syncthreads();

  const float* xwb = xw + (long)b * TC * G4 + j;
  float x0 = xwb[0], x1 = xwb[256], x2 = xwb[512], x3 = xwb[768];
  float hm_prev = 0.f;

  for (int tc = 0; tc < TC; tc++) {
    // prefetch next step's xw early (hidden under the dot chain)
    const long nx = (long)(tc + 1 < TC ? tc + 1 : tc) * G4;
    float n0 = xwb[nx], n1 = xwb[nx + 256], n2 = xwb[nx + 512], n3 = xwb[nx + 768];

    // store PREVIOUS step's output now, so the vmcnt drain at the barrier
    // overlaps with this step's compute
    if (tc > 0) {
      if (ychunk) ychunk[(b * TC + tc - 1) * H_ + j] = (_Float16)hm_prev;
      else        out[(long)(b * T_ + t0 + tc - 1) * H_ + j] = hm_prev;
    }

    const uint4* hp = (const uint4*)hsb[tc & 1];
    float a0 = x0, a1 = x1, a2 = x2, a3 = x3;

    C24(DOTC)

#pragma unroll
    for (int q = 0; q < 8; q++) {
      uint4 hv  = hp[24 + q];                    // broadcast read
      uint4 t0v = wt_lds[q * 1024 + j];          // lane-striped, conflict-free
      uint4 t1v = wt_lds[q * 1024 + j + 256];
      uint4 t2v = wt_lds[q * 1024 + j + 512];
      uint4 t3v = wt_lds[q * 1024 + j + 768];
      a0 = dot2f(t0v.x, hv.x, a0); a1 = dot2f(t1v.x, hv.x, a1);
      a2 = dot2f(t2v.x, hv.x, a2); a3 = dot2f(t3v.x, hv.x, a3);
      a0 = dot2f(t0v.y, hv.y, a0); a1 = dot2f(t1v.y, hv.y, a1);
      a2 = dot2f(t2v.y, hv.y, a2); a3 = dot2f(t3v.y, hv.y, a3);
      a0 = dot2f(t0v.z, hv.z, a0); a1 = dot2f(t1v.z, hv.z, a1);
      a2 = dot2f(t2v.z, hv.z, a2); a3 = dot2f(t3v.z, hv.z, a3);
      a0 = dot2f(t0v.w, hv.w, a0); a1 = dot2f(t1v.w, hv.w, a1);
      a2 = dot2f(t2v.w, hv.w, a2); a3 = dot2f(t3v.w, hv.w, a3);
    }

    // gate order: a0=i[j], a1=f[j], a2=g[j], a3=o[j]  (all local to this thread)
    float ci = sigm(a0), cf = sigm(a1), cg = tanh_fast(a2), co = sigm(a3);
    c_reg = cf * c_reg + ci * cg;
    h_reg = co * tanh_fast(c_reg);
    ((unsigned short*)&hsb[(tc + 1) & 1][0])[j] = h16bits(h_reg);
    hm_prev = h_reg * mk;
    x0 = n0; x1 = n1; x2 = n2; x3 = n3;
    __syncthreads();
  }

  // final output element (tc = TC-1)
  if (ychunk) ychunk[(b * TC + TC - 1) * H_ + j] = (_Float16)hm_prev;
  else        out[(long)(b * T_ + t0 + TC - 1) * H_ + j] = hm_prev;

  hstate[b * 256 + j] = h_reg;
  cstate[b * 256 + j] = c_reg;
  if (hn) { hn[b * 256 + j] = h_reg; cn[b * 256 + j] = c_reg; }
}

// ---------------- host launch ----------------
extern "C" void kernel_launch(void* const* d_in, const int* in_sizes, int n_in,
                              void* d_out, int out_size, void* d_ws, size_t ws_size,
                              hipStream_t stream) {
  const float* x     = (const float*)d_in[0];
  const float* Wih0  = (const float*)d_in[1];
  const float* Whh0  = (const float*)d_in[2];
  const float* bih0  = (const float*)d_in[3];
  const float* bhh0  = (const float*)d_in[4];
  const float* mask0 = (const float*)d_in[5];
  const float* Wih1  = (const float*)d_in[6];
  const float* Whh1  = (const float*)d_in[7];
  const float* bih1  = (const float*)d_in[8];
  const float* bhh1  = (const float*)d_in[9];
  const float* mask1 = (const float*)d_in[10];

  float* out = (float*)d_out;
  float* hn  = out + (long)B_ * T_ * H_;   // [2][64][256]
  float* cn  = hn + 2 * B_ * H_;

  char* w = (char*)d_ws;
  uint4*    wregg0 = (uint4*)w;      w += 384 << 10;   // [24][1024] uint4
  uint4*    wldsg0 = (uint4*)w;      w += 128 << 10;   // [8][1024] uint4
  uint4*    wregg1 = (uint4*)w;      w += 384 << 10;
  uint4*    wldsg1 = (uint4*)w;      w += 128 << 10;
  _Float16* wf0    = (_Float16*)w;   w += 256 << 10;   // [1024][128]
  _Float16* wf1    = (_Float16*)w;   w += 512 << 10;   // [1024][256]
  float*    bias0  = (float*)w;      w += 4 << 10;
  float*    bias1  = (float*)w;      w += 4 << 10;
  float*    h0s    = (float*)w;      w += 64 << 10;
  float*    c0s    = (float*)w;      w += 64 << 10;
  float*    h1s    = (float*)w;      w += 64 << 10;
  float*    c1s    = (float*)w;      w += 64 << 10;
  float*    xwbuf  = (float*)w;      w += (long)B_ * TC * G4 * 4;   // 32 MB
  _Float16* ybuf   = (_Float16*)w;   w += (long)B_ * TC * H_ * 2;   // 4 MB

  // zero h/c states (contiguous 256KB)
  hipMemsetAsync(h0s, 0, 4 * (64 << 10), stream);

  // weight prep
  prep_w<<<128, 256, 0, stream>>>(Whh0, wregg0, wldsg0);
  prep_w<<<128, 256, 0, stream>>>(Whh1, wregg1, wldsg1);
  prep_f16<<<512, 256, 0, stream>>>(Wih0, wf0, G4 * I_);
  prep_f16<<<1024, 256, 0, stream>>>(Wih1, wf1, G4 * H_);
  prep_bias<<<4, 256, 0, stream>>>(bih0, bhh0, bias0);
  prep_bias<<<4, 256, 0, stream>>>(bih1, bhh1, bias1);

  const int nchunk = T_ / TC;  // 16
  for (int k = 0; k < nchunk; k++) {
    int t0 = k * TC;
    bool last = (k == nchunk - 1);
    proj_kernel<I_, true><<<dim3(B_ * TC / 64, G4 / 64), 256, 0, stream>>>(
        x, wf0, bias0, xwbuf, t0);
    scan_kernel<<<B_, 256, 0, stream>>>(xwbuf, wregg0, wldsg0, mask0, h0s, c0s,
                                        ybuf, nullptr,
                                        last ? hn : nullptr, last ? cn : nullptr, t0);
    proj_kernel<H_, false><<<dim3(B_ * TC / 64, G4 / 64), 256, 0, stream>>>(
        ybuf, wf1, bias1, xwbuf, t0);
    scan_kernel<<<B_, 256, 0, stream>>>(xwbuf, wregg1, wldsg1, mask1, h1s, c1s,
                                        nullptr, out,
                                        last ? hn + B_ * H_ : nullptr,
                                        last ? cn + B_ * H_ : nullptr, t0);
  }
}

// Round 5
// 9578.517 us; speedup vs baseline: 1.5507x; 1.5507x over previous
//
#include <hip/hip_runtime.h>

#define B_  64
#define T_  2048
#define I_  128
#define H_  256
#define G4  1024   // 4*H
#define TC  128    // timestep chunk

typedef float    f32x4 __attribute__((ext_vector_type(4)));
typedef _Float16 f16x8 __attribute__((ext_vector_type(8)));
typedef _Float16 f16x2 __attribute__((ext_vector_type(2)));

__device__ __forceinline__ float dot2f(unsigned w, unsigned h, float acc) {
#if __has_builtin(__builtin_amdgcn_fdot2)
  return __builtin_amdgcn_fdot2(__builtin_bit_cast(f16x2, w),
                                __builtin_bit_cast(f16x2, h), acc, false);
#else
  f16x2 a = __builtin_bit_cast(f16x2, w), b = __builtin_bit_cast(f16x2, h);
  return acc + (float)a[0] * (float)b[0] + (float)a[1] * (float)b[1];
#endif
}

__device__ __forceinline__ unsigned short h16bits(float f) {
  return __builtin_bit_cast(unsigned short, (_Float16)f);
}
__device__ __forceinline__ float sigm(float x) { return 1.f / (1.f + __expf(-x)); }
__device__ __forceinline__ float tanh_fast(float x) { return 2.f / (1.f + __expf(-2.f * x)) - 1.f; }

// ---------------- prep kernels ----------------

// W_hh [1024][256] f32 -> packed f16x2 dwords, split into:
//   wregg: [24][1024] uint4  (k-dwords 0..95  -> register-resident in scan)
//   wldsg: [8][1024]  uint4  (k-dwords 96..127 -> LDS-resident in scan)
__global__ void prep_w(const float* __restrict__ Whh,
                       uint4* __restrict__ wregg, uint4* __restrict__ wldsg) {
  int idx = blockIdx.x * 256 + threadIdx.x;   // 0..32767
  if (idx >= 32 * 1024) return;
  int c4 = idx >> 10, r = idx & 1023;         // c4: uint4 index 0..31 along k
  unsigned q[4];
#pragma unroll
  for (int m = 0; m < 4; m++) {
    int kd = 4 * c4 + m;                      // dword index 0..127
    unsigned lo = h16bits(Whh[r * 256 + 2 * kd]);
    unsigned hi = h16bits(Whh[r * 256 + 2 * kd + 1]);
    q[m] = lo | (hi << 16);
  }
  uint4 v = make_uint4(q[0], q[1], q[2], q[3]);
  if (c4 < 24) wregg[c4 * 1024 + r] = v;
  else         wldsg[(c4 - 24) * 1024 + r] = v;
}

__global__ void prep_f16(const float* __restrict__ src, _Float16* __restrict__ dst, int n) {
  int i = blockIdx.x * 256 + threadIdx.x;
  if (i < n) dst[i] = (_Float16)src[i];
}

__global__ void prep_bias(const float* __restrict__ bi, const float* __restrict__ bh,
                          float* __restrict__ bias) {
  int i = blockIdx.x * 256 + threadIdx.x;
  if (i < G4) bias[i] = bi[i] + bh[i];
}

// ---------------- projection GEMM (f16 MFMA) ----------------
template <int K, bool SRC_F32>
__global__ __launch_bounds__(256) void proj_kernel(const void* __restrict__ Asrc,
                                                   const _Float16* __restrict__ Wf,
                                                   const float* __restrict__ bias,
                                                   float* __restrict__ xw, int t0) {
  const int m  = blockIdx.x;        // M-tile (64 rows)
  const int n0 = blockIdx.y * 64;   // N-tile base
  const int tid = threadIdx.x;
  const int lane = tid & 63, wv = tid >> 6;

  __shared__ _Float16 As[64][40];
  __shared__ _Float16 Bs[64][40];

  f32x4 acc[4] = {f32x4{0,0,0,0}, f32x4{0,0,0,0}, f32x4{0,0,0,0}, f32x4{0,0,0,0}};

  const int r  = tid >> 2;
  const int kq = (tid & 3) * 8;
  const int r_g = m * 64 + r;
  const int b  = r_g >> 7;          // TC = 128
  const int tc = r_g & (TC - 1);
  long arow;
  if (SRC_F32) arow = (long)(b * T_ + t0 + tc) * K;
  else         arow = (long)r_g * K;

  for (int k0 = 0; k0 < K; k0 += 32) {
    if (SRC_F32) {
      const float* ap = (const float*)Asrc + arow + k0 + kq;
      float4 a0 = *(const float4*)ap;
      float4 a1 = *(const float4*)(ap + 4);
      _Float16* d = &As[r][kq];
      d[0] = (_Float16)a0.x; d[1] = (_Float16)a0.y; d[2] = (_Float16)a0.z; d[3] = (_Float16)a0.w;
      d[4] = (_Float16)a1.x; d[5] = (_Float16)a1.y; d[6] = (_Float16)a1.z; d[7] = (_Float16)a1.w;
    } else {
      const _Float16* ap = (const _Float16*)Asrc + arow + k0 + kq;
      *(uint4*)&As[r][kq] = *(const uint4*)ap;
    }
    *(uint4*)&Bs[r][kq] = *(const uint4*)(Wf + (long)(n0 + r) * K + k0 + kq);
    __syncthreads();

    f16x8 av = *(const f16x8*)&As[wv * 16 + (lane & 15)][(lane >> 4) * 8];
#pragma unroll
    for (int q = 0; q < 4; q++) {
      f16x8 bv = *(const f16x8*)&Bs[q * 16 + (lane & 15)][(lane >> 4) * 8];
      acc[q] = __builtin_amdgcn_mfma_f32_16x16x32_f16(av, bv, acc[q], 0, 0, 0);
    }
    __syncthreads();
  }

  const int row_in = wv * 16 + ((lane >> 4) << 2);
  const int col_in = lane & 15;
#pragma unroll
  for (int q = 0; q < 4; q++) {
#pragma unroll
    for (int i = 0; i < 4; i++) {
      int rr = m * 64 + row_in + i;
      int cc = n0 + q * 16 + col_in;
      xw[(long)rr * G4 + cc] = acc[q][i] + bias[cc];
    }
  }
}

// ---------------- recurrent scan ----------------
// One block (512 threads, 8 waves) per batch element.
// Thread t: p = t&255, s = t>>8. Owns gate rows r0 = p + s*256, r1 = r0 + 512:
//   s=0 -> (i[p], g[p]);  s=1 -> (f[p], o[p]) and the (c[p], h[p]) state.
// W head: 2 rows x 24 uint4 = 192 dwords/thread, register-resident (fits the
// 256-ArchVGPR/lane cap; rounds 2-4 failed because 384 dwords cannot fit).
// W tail: 8 chunks in 128 KB LDS.

#define C24(X) X(0) X(1) X(2) X(3) X(4) X(5) X(6) X(7) X(8) X(9) X(10) X(11) \
               X(12) X(13) X(14) X(15) X(16) X(17) X(18) X(19) X(20) X(21) X(22) X(23)

#define LOADC(c) \
  uint4 wA_##c = wregg[(c) * 1024 + r0]; \
  uint4 wB_##c = wregg[(c) * 1024 + r1];

// Pin each loaded dword as an opaque register value (not rematerializable).
#define PINC(c) \
  asm volatile("" : "+v"(wA_##c.x), "+v"(wA_##c.y), "+v"(wA_##c.z), "+v"(wA_##c.w), \
                    "+v"(wB_##c.x), "+v"(wB_##c.y), "+v"(wB_##c.z), "+v"(wB_##c.w));

#define DOTC(c) { uint4 hv = hs4[c]; \
  a0 = dot2f(wA_##c.x, hv.x, a0); a1 = dot2f(wB_##c.x, hv.x, a1); \
  a0 = dot2f(wA_##c.y, hv.y, a0); a1 = dot2f(wB_##c.y, hv.y, a1); \
  a0 = dot2f(wA_##c.z, hv.z, a0); a1 = dot2f(wB_##c.z, hv.z, a1); \
  a0 = dot2f(wA_##c.w, hv.w, a0); a1 = dot2f(wB_##c.w, hv.w, a1); }

__global__ __launch_bounds__(512, 2) void scan_kernel(
    const float* __restrict__ xw,      // [B*TC][1024] chunk
    const uint4* __restrict__ wregg,   // [24][1024]
    const uint4* __restrict__ wldsg,   // [8][1024]
    const float* __restrict__ mask,    // [B][256]
    float* __restrict__ hstate, float* __restrict__ cstate,  // [B][256]
    _Float16* __restrict__ ychunk,     // layer0 out chunk (or null)
    float* __restrict__ out,           // layer1: d_out base (or null)
    float* __restrict__ hn, float* __restrict__ cn,          // last chunk only
    int t0) {
  const int b = blockIdx.x;
  const int t = threadIdx.x;
  const int p = t & 255;
  const int s = t >> 8;
  const int r0 = p + s * 256;
  const int r1 = r0 + 512;

  __shared__ uint4 wt_lds[8 * 1024];               // 128KB W tail, [q][row]
  __shared__ __align__(16) unsigned short hsmem[256];  // h packed f16
  __shared__ float pig[256];                       // sigm(i)*tanh(g) exchange

  // stage W tail into LDS (coalesced, conflict-free)
#pragma unroll
  for (int i = 0; i < 16; i++)
    wt_lds[i * 512 + t] = wldsg[i * 512 + t];

  // W head into 48 named uint4 (192 VGPRs), pinned against remat
  C24(LOADC)
  C24(PINC)

  float c_reg = 0.f, h_reg = 0.f, mk = 0.f;
  if (s == 1) {
    c_reg = cstate[b * 256 + p];
    mk    = mask[b * 256 + p];
  } else {
    hsmem[p] = h16bits(hstate[b * 256 + p]);
  }
  __syncthreads();

  const uint4* hs4 = (const uint4*)hsmem;
  const float* xwp = xw + (long)b * TC * G4;
  float x0 = xwp[r0], x1 = xwp[r1];
  float hm_prev = 0.f;

  for (int tc = 0; tc < TC; tc++) {
    // prefetch next step's xw early (hidden under the dot chain)
    const long nx = (long)(tc + 1 < TC ? tc + 1 : tc) * G4;
    float n0 = xwp[nx + r0], n1 = xwp[nx + r1];

    // store PREVIOUS step's output during this step's compute
    if (s == 1 && tc > 0) {
      if (ychunk) ychunk[(b * TC + tc - 1) * H_ + p] = (_Float16)hm_prev;
      else        out[(long)(b * T_ + t0 + tc - 1) * H_ + p] = hm_prev;
    }

    float a0 = x0, a1 = x1;

    C24(DOTC)

#pragma unroll
    for (int q = 0; q < 8; q++) {
      uint4 hv = hs4[24 + q];                 // broadcast read
      uint4 tA = wt_lds[q * 1024 + r0];       // lane-striped, conflict-free
      uint4 tB = wt_lds[q * 1024 + r1];
      a0 = dot2f(tA.x, hv.x, a0); a1 = dot2f(tB.x, hv.x, a1);
      a0 = dot2f(tA.y, hv.y, a0); a1 = dot2f(tB.y, hv.y, a1);
      a0 = dot2f(tA.z, hv.z, a0); a1 = dot2f(tB.z, hv.z, a1);
      a0 = dot2f(tA.w, hv.w, a0); a1 = dot2f(tB.w, hv.w, a1);
    }

    if (s == 0) {
      // a0 = pre_i[p], a1 = pre_g[p]
      pig[p] = sigm(a0) * tanh_fast(a1);
    }
    __syncthreads();
    if (s == 1) {
      // a0 = pre_f[p], a1 = pre_o[p]
      c_reg = sigm(a0) * c_reg + pig[p];
      h_reg = sigm(a1) * tanh_fast(c_reg);
      hsmem[p] = h16bits(h_reg);
      hm_prev = h_reg * mk;
    }
    x0 = n0; x1 = n1;
    __syncthreads();
  }

  if (s == 1) {
    if (ychunk) ychunk[(b * TC + TC - 1) * H_ + p] = (_Float16)hm_prev;
    else        out[(long)(b * T_ + t0 + TC - 1) * H_ + p] = hm_prev;
    hstate[b * 256 + p] = h_reg;
    cstate[b * 256 + p] = c_reg;
    if (hn) { hn[b * 256 + p] = h_reg; cn[b * 256 + p] = c_reg; }
  }
}

// ---------------- host launch ----------------
extern "C" void kernel_launch(void* const* d_in, const int* in_sizes, int n_in,
                              void* d_out, int out_size, void* d_ws, size_t ws_size,
                              hipStream_t stream) {
  const float* x     = (const float*)d_in[0];
  const float* Wih0  = (const float*)d_in[1];
  const float* Whh0  = (const float*)d_in[2];
  const float* bih0  = (const float*)d_in[3];
  const float* bhh0  = (const float*)d_in[4];
  const float* mask0 = (const float*)d_in[5];
  const float* Wih1  = (const float*)d_in[6];
  const float* Whh1  = (const float*)d_in[7];
  const float* bih1  = (const float*)d_in[8];
  const float* bhh1  = (const float*)d_in[9];
  const float* mask1 = (const float*)d_in[10];

  float* out = (float*)d_out;
  float* hn  = out + (long)B_ * T_ * H_;   // [2][64][256]
  float* cn  = hn + 2 * B_ * H_;

  char* w = (char*)d_ws;
  uint4*    wregg0 = (uint4*)w;      w += 384 << 10;   // [24][1024] uint4
  uint4*    wldsg0 = (uint4*)w;      w += 128 << 10;   // [8][1024] uint4
  uint4*    wregg1 = (uint4*)w;      w += 384 << 10;
  uint4*    wldsg1 = (uint4*)w;      w += 128 << 10;
  _Float16* wf0    = (_Float16*)w;   w += 256 << 10;   // [1024][128]
  _Float16* wf1    = (_Float16*)w;   w += 512 << 10;   // [1024][256]
  float*    bias0  = (float*)w;      w += 4 << 10;
  float*    bias1  = (float*)w;      w += 4 << 10;
  float*    h0s    = (float*)w;      w += 64 << 10;
  float*    c0s    = (float*)w;      w += 64 << 10;
  float*    h1s    = (float*)w;      w += 64 << 10;
  float*    c1s    = (float*)w;      w += 64 << 10;
  float*    xwbuf  = (float*)w;      w += (long)B_ * TC * G4 * 4;   // 32 MB
  _Float16* ybuf   = (_Float16*)w;   w += (long)B_ * TC * H_ * 2;   // 4 MB

  // zero h/c states (contiguous 256KB)
  hipMemsetAsync(h0s, 0, 4 * (64 << 10), stream);

  // weight prep
  prep_w<<<128, 256, 0, stream>>>(Whh0, wregg0, wldsg0);
  prep_w<<<128, 256, 0, stream>>>(Whh1, wregg1, wldsg1);
  prep_f16<<<512, 256, 0, stream>>>(Wih0, wf0, G4 * I_);
  prep_f16<<<1024, 256, 0, stream>>>(Wih1, wf1, G4 * H_);
  prep_bias<<<4, 256, 0, stream>>>(bih0, bhh0, bias0);
  prep_bias<<<4, 256, 0, stream>>>(bih1, bhh1, bias1);

  const int nchunk = T_ / TC;  // 16
  for (int k = 0; k < nchunk; k++) {
    int t0 = k * TC;
    bool last = (k == nchunk - 1);
    proj_kernel<I_, true><<<dim3(B_ * TC / 64, G4 / 64), 256, 0, stream>>>(
        x, wf0, bias0, xwbuf, t0);
    scan_kernel<<<B_, 512, 0, stream>>>(xwbuf, wregg0, wldsg0, mask0, h0s, c0s,
                                        ybuf, nullptr,
                                        last ? hn : nullptr, last ? cn : nullptr, t0);
    proj_kernel<H_, false><<<dim3(B_ * TC / 64, G4 / 64), 256, 0, stream>>>(
        ybuf, wf1, bias1, xwbuf, t0);
    scan_kernel<<<B_, 512, 0, stream>>>(xwbuf, wregg1, wldsg1, mask1, h1s, c1s,
                                        nullptr, out,
                                        last ? hn + B_ * H_ : nullptr,
                                        last ? cn + B_ * H_ : nullptr, t0);
  }
}